// Round 10
// baseline (341.243 us; speedup 1.0000x reference)
//
#include <hip/hip_runtime.h>
#include <hip/hip_bf16.h>

#define SEQ 16384
#define DIM 1280
#define NHEAD 16
#define HD 80
#define NWIN 256   // SEQ / 64
#define QKV_N 3840 // 3 * DIM
#define GK 1280    // K of both GEMMs
#define NTK 40     // GK / 32

typedef __attribute__((ext_vector_type(8))) short bf16x8;
typedef __attribute__((ext_vector_type(8))) unsigned short ushort8;
typedef __attribute__((ext_vector_type(4))) float f32x4;

__device__ inline unsigned short f2bf(float x) {
    union { __hip_bfloat16 b; unsigned short u; } cv;
    cv.b = __float2bfloat16(x);
    return cv.u;
}
__device__ inline float bf2f(unsigned short u) {
    union { unsigned int i; float f; } cv;
    cv.i = ((unsigned int)u) << 16;
    return cv.f;
}

// async global->LDS, 16B per lane, wave-uniform LDS base + lane*16
#define GLD16(g, l) __builtin_amdgcn_global_load_lds( \
    (const __attribute__((address_space(1))) void*)(g), \
    (__attribute__((address_space(3))) void*)(l), 16, 0, 0)

#define SBAR() asm volatile("s_barrier" ::: "memory")

// ---------------------------------------------------------------------------
// f32 -> bf16 convert, 8 elems/thread, vectorized
// ---------------------------------------------------------------------------
__global__ __launch_bounds__(256) void cvt_f32_bf16(const float* __restrict__ src,
                                                    unsigned short* __restrict__ dst,
                                                    long n) {
    long i = ((long)blockIdx.x * 256 + threadIdx.x) * 8;
    if (i >= n) return;
    const float4 a = *(const float4*)(src + i);
    const float4 b = *(const float4*)(src + i + 4);
    ushort8 o;
    o[0] = f2bf(a.x); o[1] = f2bf(a.y); o[2] = f2bf(a.z); o[3] = f2bf(a.w);
    o[4] = f2bf(b.x); o[5] = f2bf(b.y); o[6] = f2bf(b.z); o[7] = f2bf(b.w);
    *(ushort8*)(dst + i) = o;
}

// ---------------------------------------------------------------------------
// TLP-oriented bf16 MFMA NT-GEMM: out[M][N] = A[M][K] @ B[N][K]^T + bias.
// 128x256 tile, BK=32, 512 threads (8 waves 2Mx4N, 64x64 out each, acc=64
// VGPR -> total ~120 <= 128 so FOUR waves/SIMD; LDS 48 KiB/block dbuf ->
// TWO blocks/CU). r5-r9 plateaued at ~43% MfmaUtil: 128-AGPR acc forced
// 2 waves/SIMD and no schedule could overlap LDS and MFMA pipes within a
// lockstep block (m131-m141 lesson). Cross-block TLP (m114) provides the
// overlap instead: partner block's MFMAs cover this block's vmcnt+barrier
// drain. Single-barrier counted loop as r7 (race-freedom identical).
// T2 swizzle adapted to 4-granule rows: LDS[row][gr] = global[row][gr ^
// (row&3)] (16B granules); read k-granule g at e = ((g ^ (l15&3))<<3).
// Wave reads whole rows (4 lanes x 4 granules) -> stride-1-like, no bank
// conflicts. T1 XCD swizzle (grids 1920/640, %8==0); T5 setprio.
// ---------------------------------------------------------------------------
template <int OUT_BF16>
__global__ __launch_bounds__(512, 4) void gemm_nt_bf16_tlp(
    const unsigned short* __restrict__ A,   // [M][GK] bf16
    const unsigned short* __restrict__ B,   // [N][GK] bf16
    const float* __restrict__ bias,         // [N]
    void* __restrict__ outp,                // [M][N] f32 or bf16
    int N, int nbx)                         // nbx = N/256
{
    __shared__ unsigned short sh[24576];    // [2][A 4096 | B 8192] elems, 48 KiB

    const int t = threadIdx.x;
    const int w = t >> 6;
    const int lane = t & 63;
    const int l15 = lane & 15;
    const int g = lane >> 4;

    // T1: XCD swizzle (gridDim.x multiple of 8)
    const int cpx = gridDim.x >> 3;
    const int bid = blockIdx.x;
    const int wg = (bid & 7) * cpx + (bid >> 3);
    const int bm = (wg / nbx) * 128;
    const int bn = (wg % nbx) * 256;

    const int wr = (w >> 2) * 64;    // wave rows [wr, wr+64)
    const int wc = (w & 3) * 64;     // wave cols [wc, wc+64)

    // staging: chunk c covers LDS elems [c*8, c*8+8); row = c>>2 (4 granules
    // of 16B per 32-elem row), granule = c&3. Pre-swizzled source granule =
    // (c&3) ^ (row&3); note c and c+512 share (c&3) and (row&3) (+128 rows).
    const int colsw = (((t & 3) ^ ((t >> 2) & 3)) << 3);   // elements
    const unsigned short* gA  = A + (size_t)(bm + (t >> 2)) * GK + colsw;
    const unsigned short* gB0 = B + (size_t)(bn + (t >> 2)) * GK + colsw;
    const unsigned short* gB1 = gB0 + (size_t)128 * GK;
    const int wub = (t & ~63) * 8;   // wave-uniform LDS elem base

    // frag reads: LDS[row*32 + e], e = ((g ^ (l15&3))<<3); row&3 == l15&3
    // for all mi/ni since wr/wc/mi*16 are multiples of 4 (full-offset XOR).
    const int esw = ((g ^ (l15 & 3)) << 3);
    int aoff[4], boff[4];
#pragma unroll
    for (int mi = 0; mi < 4; ++mi) aoff[mi] = (wr + mi * 16 + l15) * 32 + esw;
#pragma unroll
    for (int ni = 0; ni < 4; ++ni) boff[ni] = 4096 + (wc + ni * 16 + l15) * 32 + esw;

    f32x4 acc[4][4];
#pragma unroll
    for (int mi = 0; mi < 4; ++mi)
#pragma unroll
        for (int ni = 0; ni < 4; ++ni)
            acc[mi][ni] = (f32x4){0.f, 0.f, 0.f, 0.f};

    // stage the 3 loads of K-tile `tile` into region tile&1
    auto stageTile = [&](int tile) {
        if (tile >= NTK) return;
        unsigned short* rg = sh + (tile & 1) * 12288 + wub;
        const int ka = tile * 32;
        GLD16(gA + ka, rg);                 // A: rows 0..127
        GLD16(gB0 + ka, rg + 4096);         // B: rows 0..127
        GLD16(gB1 + ka, rg + 8192);         // B: rows 128..255
    };

    // prologue
    stageTile(0);

    for (int kt = 0; kt < NTK; ++kt) {
        const unsigned short* base = sh + (kt & 1) * 12288;

        asm volatile("s_waitcnt vmcnt(0)" ::: "memory");  // tile kt staged
        SBAR();                                           // block-wide visible
        stageTile(kt + 1);                                // region ~cur only

        bf16x8 af[4], bfr[4];
#pragma unroll
        for (int ni = 0; ni < 4; ++ni) bfr[ni] = *(const bf16x8*)(base + boff[ni]);
#pragma unroll
        for (int mi = 0; mi < 4; ++mi) af[mi] = *(const bf16x8*)(base + aoff[mi]);

        __builtin_amdgcn_s_setprio(1);
#pragma unroll
        for (int mi = 0; mi < 4; ++mi)
#pragma unroll
            for (int ni = 0; ni < 4; ++ni)
                acc[mi][ni] = __builtin_amdgcn_mfma_f32_16x16x32_bf16(
                    af[mi], bfr[ni], acc[mi][ni], 0, 0, 0);
        __builtin_amdgcn_s_setprio(0);
    }

    // ---- epilogue: C/D layout col=l15, row=g*4+reg ----
    const int orow = bm + wr + g * 4;
    const int ocol = bn + wc + l15;
    float bv[4];
#pragma unroll
    for (int ni = 0; ni < 4; ++ni) bv[ni] = bias[ocol + ni * 16];
#pragma unroll
    for (int mi = 0; mi < 4; ++mi)
#pragma unroll
        for (int ni = 0; ni < 4; ++ni)
#pragma unroll
            for (int r = 0; r < 4; ++r) {
                const int row = orow + mi * 16 + r;
                const int col = ocol + ni * 16;
                const float v = acc[mi][ni][r] + bv[ni];
                if (OUT_BF16)
                    ((unsigned short*)outp)[(size_t)row * N + col] = f2bf(v);
                else
                    ((float*)outp)[(size_t)row * N + col] = v;
            }
}

// ---------------------------------------------------------------------------
// MFMA windowed attention (unchanged)
// ---------------------------------------------------------------------------
__global__ __launch_bounds__(256) void win_attn_mfma(
    const unsigned short* __restrict__ qkv,  // [S][3840] bf16
    const float* __restrict__ cosb,          // [S][80]
    const float* __restrict__ sinb,          // [S][80]
    const float* __restrict__ mask,          // [NWIN][64][64]
    unsigned short* __restrict__ attn_out)   // [S][1280] bf16
{
    const int h = blockIdx.x;
    const int win = blockIdx.y;
    const int t = threadIdx.x;
    const int w = t >> 6;
    const int lane = t & 63;
    const int l15 = lane & 15;
    const int g = lane >> 4;

    __shared__ unsigned short Qs[64 * 104];
    __shared__ unsigned short Ks[64 * 104];
    __shared__ unsigned short Vt[80 * 88];
    unsigned short* P = Qs;

    const float scale = 0.11180339887498949f;  // 1/sqrt(80)

    for (int c = t; c < 640; c += 256) {
        const int qk = c / 320;
        const int cc = c % 320;
        const int tok = cc / 5;
        const int dd = (cc % 5) * 8;
        const int tokg = win * 64 + tok;
        const size_t gb = (size_t)tokg * QKV_N + h * HD + qk * DIM;
        const bf16x8 lo = *(const bf16x8*)(qkv + gb + dd);
        const bf16x8 hi = *(const bf16x8*)(qkv + gb + dd + 40);
        float cl[8], sl[8], ch[8], sh[8];
        *(float4*)cl = *(const float4*)(cosb + tokg * HD + dd);
        *(float4*)(cl + 4) = *(const float4*)(cosb + tokg * HD + dd + 4);
        *(float4*)sl = *(const float4*)(sinb + tokg * HD + dd);
        *(float4*)(sl + 4) = *(const float4*)(sinb + tokg * HD + dd + 4);
        *(float4*)ch = *(const float4*)(cosb + tokg * HD + dd + 40);
        *(float4*)(ch + 4) = *(const float4*)(cosb + tokg * HD + dd + 44);
        *(float4*)sh = *(const float4*)(sinb + tokg * HD + dd + 40);
        *(float4*)(sh + 4) = *(const float4*)(sinb + tokg * HD + dd + 44);
        ushort8 olo, ohi;
#pragma unroll
        for (int j = 0; j < 8; ++j) {
            const float x1 = bf2f((unsigned short)lo[j]);
            const float x2 = bf2f((unsigned short)hi[j]);
            float rl = x1 * cl[j] - x2 * sl[j];
            float rh = x2 * ch[j] + x1 * sh[j];
            if (qk == 0) { rl *= scale; rh *= scale; }
            olo[j] = f2bf(rl);
            ohi[j] = f2bf(rh);
        }
        unsigned short* base = (qk ? Ks : Qs) + tok * 104 + dd;
        *(ushort8*)base = olo;
        *(ushort8*)(base + 40) = ohi;
    }
    {
        const int tile = t >> 7, row = (t >> 1) & 63, half = t & 1;
        ushort8 z = (ushort8)0;
        *(ushort8*)((tile ? Ks : Qs) + row * 104 + 80 + half * 8) = z;
    }
    for (int c = t; c < 640; c += 256) {
        const int tok = c / 10;
        const int dd = (c % 10) * 8;
        const bf16x8 vv = *(const bf16x8*)(qkv +
            (size_t)(win * 64 + tok) * QKV_N + h * HD + 2 * DIM + dd);
#pragma unroll
        for (int j = 0; j < 8; ++j)
            Vt[(dd + j) * 88 + tok] = (unsigned short)vv[j];
    }
    __syncthreads();

    f32x4 acc[4];
#pragma unroll
    for (int n = 0; n < 4; ++n) acc[n] = (f32x4){0.f, 0.f, 0.f, 0.f};
#pragma unroll
    for (int ks = 0; ks < 3; ++ks) {
        const int k0 = ks * 32;
        const bf16x8 af = *(const bf16x8*)(Qs + (w * 16 + l15) * 104 + k0 + g * 8);
#pragma unroll
        for (int n = 0; n < 4; ++n) {
            const bf16x8 bfr = *(const bf16x8*)(Ks + (n * 16 + l15) * 104 + k0 + g * 8);
            acc[n] = __builtin_amdgcn_mfma_f32_16x16x32_bf16(af, bfr, acc[n], 0, 0, 0);
        }
    }

    const float* mp = mask + (size_t)win * 4096;
    float pr[4][4];
#pragma unroll
    for (int r = 0; r < 4; ++r) {
        const int row = w * 16 + g * 4 + r;
        float v[4];
#pragma unroll
        for (int n = 0; n < 4; ++n)
            v[n] = acc[n][r] + mp[row * 64 + n * 16 + l15];
        float mx = fmaxf(fmaxf(v[0], v[1]), fmaxf(v[2], v[3]));
        mx = fmaxf(mx, __shfl_xor(mx, 1));
        mx = fmaxf(mx, __shfl_xor(mx, 2));
        mx = fmaxf(mx, __shfl_xor(mx, 4));
        mx = fmaxf(mx, __shfl_xor(mx, 8));
        float sum = 0.f;
#pragma unroll
        for (int n = 0; n < 4; ++n) { v[n] = __expf(v[n] - mx); sum += v[n]; }
        sum += __shfl_xor(sum, 1);
        sum += __shfl_xor(sum, 2);
        sum += __shfl_xor(sum, 4);
        sum += __shfl_xor(sum, 8);
        const float inv = 1.0f / sum;
#pragma unroll
        for (int n = 0; n < 4; ++n) pr[r][n] = v[n] * inv;
    }

    __syncthreads();
#pragma unroll
    for (int r = 0; r < 4; ++r)
#pragma unroll
        for (int n = 0; n < 4; ++n)
            P[(w * 16 + g * 4 + r) * 72 + n * 16 + l15] = f2bf(pr[r][n]);
    __syncthreads();

    f32x4 ao[5];
#pragma unroll
    for (int n = 0; n < 5; ++n) ao[n] = (f32x4){0.f, 0.f, 0.f, 0.f};
#pragma unroll
    for (int ks = 0; ks < 2; ++ks) {
        const int k0 = ks * 32;
        const bf16x8 pa = *(const bf16x8*)(P + (w * 16 + l15) * 72 + k0 + g * 8);
#pragma unroll
        for (int n = 0; n < 5; ++n) {
            const bf16x8 bv = *(const bf16x8*)(Vt + (n * 16 + l15) * 88 + k0 + g * 8);
            ao[n] = __builtin_amdgcn_mfma_f32_16x16x32_bf16(pa, bv, ao[n], 0, 0, 0);
        }
    }

#pragma unroll
    for (int n = 0; n < 5; ++n)
#pragma unroll
        for (int r = 0; r < 4; ++r) {
            const int row = win * 64 + w * 16 + g * 4 + r;
            attn_out[(size_t)row * DIM + h * HD + n * 16 + l15] = f2bf(ao[n][r]);
        }
}

// ---------------------------------------------------------------------------
extern "C" void kernel_launch(void* const* d_in, const int* in_sizes, int n_in,
                              void* d_out, int out_size, void* d_ws, size_t ws_size,
                              hipStream_t stream) {
    const float* hidden = (const float*)d_in[0];
    const float* masks  = (const float*)d_in[1];
    const float* cosb   = (const float*)d_in[2];
    const float* sinb   = (const float*)d_in[3];
    const float* qkv_w  = (const float*)d_in[4];
    const float* qkv_b  = (const float*)d_in[5];
    const float* proj_w = (const float*)d_in[6];
    const float* proj_b = (const float*)d_in[7];
    float* out = (float*)d_out;

    unsigned short* qkv_bf    = (unsigned short*)d_ws;                  // [SEQ][3840]
    unsigned short* attn_bf   = qkv_bf    + (size_t)SEQ * QKV_N;        // [SEQ][1280]
    unsigned short* hidden_bf = attn_bf   + (size_t)SEQ * DIM;          // [SEQ][1280]
    unsigned short* qkvw_bf   = hidden_bf + (size_t)SEQ * DIM;          // [3840][1280]
    unsigned short* projw_bf  = qkvw_bf   + (size_t)QKV_N * DIM;        // [1280][1280]

    {
        const long n0 = (long)SEQ * DIM;
        const long n1 = (long)QKV_N * DIM;
        const long n2 = (long)DIM * DIM;
        cvt_f32_bf16<<<(int)(n0 / (8 * 256)), 256, 0, stream>>>(hidden, hidden_bf, n0);
        cvt_f32_bf16<<<(int)(n1 / (8 * 256)), 256, 0, stream>>>(qkv_w, qkvw_bf, n1);
        cvt_f32_bf16<<<(int)(n2 / (8 * 256)), 256, 0, stream>>>(proj_w, projw_bf, n2);
    }
    {   // QKV projection: M=16384 -> 128 row-blocks x 15 col-blocks = 1920
        gemm_nt_bf16_tlp<1><<<dim3(1920), 512, 0, stream>>>(
            hidden_bf, qkvw_bf, qkv_b, (void*)qkv_bf, QKV_N, QKV_N / 256);
    }
    {
        dim3 grid(NHEAD, NWIN);
        win_attn_mfma<<<grid, 256, 0, stream>>>(qkv_bf, cosb, sinb, masks, attn_bf);
    }
    {   // output projection: 128 x 5 = 640 blocks
        gemm_nt_bf16_tlp<0><<<dim3(640), 512, 0, stream>>>(
            attn_bf, projw_bf, proj_b, (void*)out, DIM, DIM / 256);
    }
}

// Round 11
// 319.032 us; speedup vs baseline: 1.0696x; 1.0696x over previous
//
#include <hip/hip_runtime.h>
#include <hip/hip_bf16.h>

#define SEQ 16384
#define DIM 1280
#define NHEAD 16
#define HD 80
#define NWIN 256   // SEQ / 64
#define QKV_N 3840 // 3 * DIM
#define GK 1280    // K of both GEMMs
#define NT 20      // GK / 64

typedef __attribute__((ext_vector_type(8))) short bf16x8;
typedef __attribute__((ext_vector_type(8))) unsigned short ushort8;
typedef __attribute__((ext_vector_type(4))) float f32x4;

__device__ inline unsigned short f2bf(float x) {
    union { __hip_bfloat16 b; unsigned short u; } cv;
    cv.b = __float2bfloat16(x);
    return cv.u;
}
__device__ inline float bf2f(unsigned short u) {
    union { unsigned int i; float f; } cv;
    cv.i = ((unsigned int)u) << 16;
    return cv.f;
}

// async global->LDS, 16B per lane, wave-uniform LDS base + lane*16
#define GLD16(g, l) __builtin_amdgcn_global_load_lds( \
    (const __attribute__((address_space(1))) void*)(g), \
    (__attribute__((address_space(3))) void*)(l), 16, 0, 0)

#define SBAR() asm volatile("s_barrier" ::: "memory")

// ---------------------------------------------------------------------------
// f32 -> bf16 convert, 8 elems/thread, vectorized
// ---------------------------------------------------------------------------
__global__ __launch_bounds__(256) void cvt_f32_bf16(const float* __restrict__ src,
                                                    unsigned short* __restrict__ dst,
                                                    long n) {
    long i = ((long)blockIdx.x * 256 + threadIdx.x) * 8;
    if (i >= n) return;
    const float4 a = *(const float4*)(src + i);
    const float4 b = *(const float4*)(src + i + 4);
    ushort8 o;
    o[0] = f2bf(a.x); o[1] = f2bf(a.y); o[2] = f2bf(a.z); o[3] = f2bf(a.w);
    o[4] = f2bf(b.x); o[5] = f2bf(b.y); o[6] = f2bf(b.z); o[7] = f2bf(b.w);
    *(ushort8*)(dst + i) = o;
}

// ---------------------------------------------------------------------------
// [QKV] r9 kernel (best known: 162 us, 0 conflicts): 256x256, BK=64, 8 waves,
// single-barrier counted loop, sw-pipelined ping-pong frags, 3-bit both-
// sides XOR swizzle, T1/T5.
// ---------------------------------------------------------------------------
template <int OUT_BF16>
__global__ __launch_bounds__(512, 2) void gemm_nt_bf16_sp(
    const unsigned short* __restrict__ A,
    const unsigned short* __restrict__ B,
    const float* __restrict__ bias,
    void* __restrict__ outp,
    int N, int nbx)                         // nbx = N/256
{
    __shared__ unsigned short sh[65536];    // 128 KiB

    const int t = threadIdx.x;
    const int w = t >> 6;
    const int lane = t & 63;
    const int l15 = lane & 15;
    const int g = lane >> 4;

    const int cpx = gridDim.x >> 3;
    const int bid = blockIdx.x;
    const int wg = (bid & 7) * cpx + (bid >> 3);
    const int bm = (wg / nbx) * 256;
    const int bn = (wg % nbx) * 256;

    const int wr = (w >> 2) * 128;
    const int wc = (w & 3) * 64;

    const int colsw = ((t & 7) * 8) ^ (((t >> 3) & 7) << 3);
    const int tr = t >> 3;
    const unsigned short* gA[4];
    const unsigned short* gB[4];
#pragma unroll
    for (int j = 0; j < 4; ++j) {
        gA[j] = A + (size_t)(bm + j * 64 + tr) * GK + colsw;
        gB[j] = B + (size_t)(bn + j * 64 + tr) * GK + colsw;
    }
    const int wub = (t & ~63) * 8;

    const int sw = (l15 & 7) << 3;
    const int fk0 = (g * 8) ^ sw;
    const int fk1 = (32 + g * 8) ^ sw;
    int arow[8], brow[4];
#pragma unroll
    for (int mi = 0; mi < 8; ++mi) arow[mi] = (wr + mi * 16 + l15) * 64;
#pragma unroll
    for (int ni = 0; ni < 4; ++ni) brow[ni] = 16384 + (wc + ni * 16 + l15) * 64;

    f32x4 acc[8][4];
#pragma unroll
    for (int mi = 0; mi < 8; ++mi)
#pragma unroll
        for (int ni = 0; ni < 4; ++ni)
            acc[mi][ni] = (f32x4){0.f, 0.f, 0.f, 0.f};

    auto stageTile = [&](int tile) {
        if (tile >= NT) return;
        unsigned short* rg = sh + (tile & 1) * 32768 + wub;
        const int ka = tile * 64;
        GLD16(gA[0] + ka, rg);
        GLD16(gA[1] + ka, rg + 4096);
        GLD16(gA[2] + ka, rg + 8192);
        GLD16(gA[3] + ka, rg + 12288);
        GLD16(gB[0] + ka, rg + 16384);
        GLD16(gB[1] + ka, rg + 20480);
        GLD16(gB[2] + ka, rg + 24576);
        GLD16(gB[3] + ka, rg + 28672);
    };

    bf16x8 afA[4], afB[4], bfrA[4], bfrB[4];

#define MFMA_QUAD(H, AF, BF)                                                  \
    __builtin_amdgcn_s_setprio(1);                                            \
    _Pragma("unroll") for (int mi = 0; mi < 4; ++mi)                          \
    _Pragma("unroll") for (int ni = 0; ni < 4; ++ni)                          \
        acc[(H) * 4 + mi][ni] = __builtin_amdgcn_mfma_f32_16x16x32_bf16(      \
            (AF)[mi], (BF)[ni], acc[(H) * 4 + mi][ni], 0, 0, 0);              \
    __builtin_amdgcn_s_setprio(0);

    stageTile(0);

    for (int kt = 0; kt < NT; ++kt) {
        const unsigned short* base = sh + (kt & 1) * 32768;

        asm volatile("s_waitcnt vmcnt(0)" ::: "memory");
        SBAR();
        stageTile(kt + 1);

#pragma unroll
        for (int ni = 0; ni < 4; ++ni) bfrA[ni] = *(const bf16x8*)(base + brow[ni] + fk0);
#pragma unroll
        for (int mi = 0; mi < 4; ++mi) afA[mi] = *(const bf16x8*)(base + arow[mi] + fk0);
#pragma unroll
        for (int mi = 0; mi < 4; ++mi) afB[mi] = *(const bf16x8*)(base + arow[4 + mi] + fk0);
        MFMA_QUAD(0, afA, bfrA);
#pragma unroll
        for (int ni = 0; ni < 4; ++ni) bfrB[ni] = *(const bf16x8*)(base + brow[ni] + fk1);
#pragma unroll
        for (int mi = 0; mi < 4; ++mi) afA[mi] = *(const bf16x8*)(base + arow[mi] + fk1);
        MFMA_QUAD(1, afB, bfrA);
#pragma unroll
        for (int mi = 0; mi < 4; ++mi) afB[mi] = *(const bf16x8*)(base + arow[4 + mi] + fk1);
        MFMA_QUAD(0, afA, bfrB);
        MFMA_QUAD(1, afB, bfrB);
    }
#undef MFMA_QUAD

    const int orow = bm + wr + g * 4;
    const int ocol = bn + wc + l15;
    float bv[4];
#pragma unroll
    for (int ni = 0; ni < 4; ++ni) bv[ni] = bias[ocol + ni * 16];
#pragma unroll
    for (int mi = 0; mi < 8; ++mi)
#pragma unroll
        for (int ni = 0; ni < 4; ++ni)
#pragma unroll
            for (int r = 0; r < 4; ++r) {
                const int row = orow + mi * 16 + r;
                const int col = ocol + ni * 16;
                const float v = acc[mi][ni][r] + bv[ni];
                if (OUT_BF16)
                    ((unsigned short*)outp)[(size_t)row * N + col] = f2bf(v);
                else
                    ((float*)outp)[(size_t)row * N + col] = v;
            }
}

// ---------------------------------------------------------------------------
// [PROJ] 128x128 TLP variant: BK=64 (64-elem rows -> the PROVEN 3-bit
// conflict-free swizzle, fixing r10's BK=32 conflicts), 256 threads =
// 4 waves (2x2, 64x64 out each, acc=64 VGPR), LDS 64 KiB dbuf -> TWO
// independent blocks/CU. Cross-block TLP: partner block's MFMAs cover this
// block's vmcnt+barrier drain (m114), and grid 1280 -> 2.5 capacity-rounds
// (83% sched eff vs 62.5% for 320x256-tiles). Single-barrier counted loop,
// race-freedom as r7. A/B probe: if this dispatch's MfmaUtil > 48%, port
// shape to QKV next round.
// ---------------------------------------------------------------------------
template <int OUT_BF16>
__global__ __launch_bounds__(256, 2) void gemm_nt_bf16_t2(
    const unsigned short* __restrict__ A,
    const unsigned short* __restrict__ B,
    const float* __restrict__ bias,
    void* __restrict__ outp,
    int N, int nbx)                         // nbx = N/128
{
    __shared__ unsigned short sh[32768];    // [2][A 8192 | B 8192] elems, 64 KiB

    const int t = threadIdx.x;
    const int w = t >> 6;
    const int lane = t & 63;
    const int l15 = lane & 15;
    const int g = lane >> 4;

    const int cpx = gridDim.x >> 3;
    const int bid = blockIdx.x;
    const int wg = (bid & 7) * cpx + (bid >> 3);
    const int bm = (wg / nbx) * 128;
    const int bn = (wg % nbx) * 128;

    const int wr = (w >> 1) * 64;    // wave rows [wr, wr+64)
    const int wc = (w & 1) * 64;     // wave cols [wc, wc+64)

    // staging: block i (i=0..3 -> A rows i*32.., i=4..7 -> B rows (i-4)*32..)
    // thread t covers row (t>>3) within the 32-row block, granule t&7.
    const int tr = t >> 3;
    const int colsw = ((t & 7) * 8) ^ (((t >> 3) & 7) << 3);  // elements
    const unsigned short* gA[4];
    const unsigned short* gB[4];
#pragma unroll
    for (int j = 0; j < 4; ++j) {
        gA[j] = A + (size_t)(bm + j * 32 + tr) * GK + colsw;
        gB[j] = B + (size_t)(bn + j * 32 + tr) * GK + colsw;
    }
    const int wub = (t & ~63) * 8;   // wave-uniform LDS elem base

    const int sw = (l15 & 7) << 3;
    const int fk0 = (g * 8) ^ sw;
    const int fk1 = (32 + g * 8) ^ sw;
    int arow[4], brow[4];
#pragma unroll
    for (int mi = 0; mi < 4; ++mi) arow[mi] = (wr + mi * 16 + l15) * 64;
#pragma unroll
    for (int ni = 0; ni < 4; ++ni) brow[ni] = 8192 + (wc + ni * 16 + l15) * 64;

    f32x4 acc[4][4];
#pragma unroll
    for (int mi = 0; mi < 4; ++mi)
#pragma unroll
        for (int ni = 0; ni < 4; ++ni)
            acc[mi][ni] = (f32x4){0.f, 0.f, 0.f, 0.f};

    // stage all 8 chunks of K-tile `tile` into region tile&1 (32 KB)
    auto stageTile = [&](int tile) {
        if (tile >= NT) return;
        unsigned short* rg = sh + (tile & 1) * 16384 + wub;
        const int ka = tile * 64;
#pragma unroll
        for (int j = 0; j < 4; ++j) {
            GLD16(gA[j] + ka, rg + j * 2048);
            GLD16(gB[j] + ka, rg + 8192 + j * 2048);
        }
    };

    bf16x8 afA[4], afB[4], bfrA[4], bfrB[4];

#define MFMA_Q16(AF, BF)                                                      \
    __builtin_amdgcn_s_setprio(1);                                            \
    _Pragma("unroll") for (int mi = 0; mi < 4; ++mi)                          \
    _Pragma("unroll") for (int ni = 0; ni < 4; ++ni)                          \
        acc[mi][ni] = __builtin_amdgcn_mfma_f32_16x16x32_bf16(                \
            (AF)[mi], (BF)[ni], acc[mi][ni], 0, 0, 0);                        \
    __builtin_amdgcn_s_setprio(0);

    stageTile(0);

    for (int kt = 0; kt < NT; ++kt) {
        const unsigned short* base = sh + (kt & 1) * 16384;

        asm volatile("s_waitcnt vmcnt(0)" ::: "memory");  // tile kt staged
        SBAR();                                           // block-wide visible
        stageTile(kt + 1);                                // region ~cur only

        // kk0 frags, prefetch kk1 frags, then MFMA both (compiler overlaps)
#pragma unroll
        for (int ni = 0; ni < 4; ++ni) bfrA[ni] = *(const bf16x8*)(base + brow[ni] + fk0);
#pragma unroll
        for (int mi = 0; mi < 4; ++mi) afA[mi] = *(const bf16x8*)(base + arow[mi] + fk0);
#pragma unroll
        for (int ni = 0; ni < 4; ++ni) bfrB[ni] = *(const bf16x8*)(base + brow[ni] + fk1);
#pragma unroll
        for (int mi = 0; mi < 4; ++mi) afB[mi] = *(const bf16x8*)(base + arow[mi] + fk1);
        MFMA_Q16(afA, bfrA);
        MFMA_Q16(afB, bfrB);
    }
#undef MFMA_Q16

    const int orow = bm + wr + g * 4;
    const int ocol = bn + wc + l15;
    float bv[4];
#pragma unroll
    for (int ni = 0; ni < 4; ++ni) bv[ni] = bias[ocol + ni * 16];
#pragma unroll
    for (int mi = 0; mi < 4; ++mi)
#pragma unroll
        for (int ni = 0; ni < 4; ++ni)
#pragma unroll
            for (int r = 0; r < 4; ++r) {
                const int row = orow + mi * 16 + r;
                const int col = ocol + ni * 16;
                const float v = acc[mi][ni][r] + bv[ni];
                if (OUT_BF16)
                    ((unsigned short*)outp)[(size_t)row * N + col] = f2bf(v);
                else
                    ((float*)outp)[(size_t)row * N + col] = v;
            }
}

// ---------------------------------------------------------------------------
// MFMA windowed attention (unchanged; ~55 us)
// ---------------------------------------------------------------------------
__global__ __launch_bounds__(256) void win_attn_mfma(
    const unsigned short* __restrict__ qkv,  // [S][3840] bf16
    const float* __restrict__ cosb,          // [S][80]
    const float* __restrict__ sinb,          // [S][80]
    const float* __restrict__ mask,          // [NWIN][64][64]
    unsigned short* __restrict__ attn_out)   // [S][1280] bf16
{
    const int h = blockIdx.x;
    const int win = blockIdx.y;
    const int t = threadIdx.x;
    const int w = t >> 6;
    const int lane = t & 63;
    const int l15 = lane & 15;
    const int g = lane >> 4;

    __shared__ unsigned short Qs[64 * 104];
    __shared__ unsigned short Ks[64 * 104];
    __shared__ unsigned short Vt[80 * 88];
    unsigned short* P = Qs;

    const float scale = 0.11180339887498949f;  // 1/sqrt(80)

    for (int c = t; c < 640; c += 256) {
        const int qk = c / 320;
        const int cc = c % 320;
        const int tok = cc / 5;
        const int dd = (cc % 5) * 8;
        const int tokg = win * 64 + tok;
        const size_t gb = (size_t)tokg * QKV_N + h * HD + qk * DIM;
        const bf16x8 lo = *(const bf16x8*)(qkv + gb + dd);
        const bf16x8 hi = *(const bf16x8*)(qkv + gb + dd + 40);
        float cl[8], sl[8], ch[8], sh[8];
        *(float4*)cl = *(const float4*)(cosb + tokg * HD + dd);
        *(float4*)(cl + 4) = *(const float4*)(cosb + tokg * HD + dd + 4);
        *(float4*)sl = *(const float4*)(sinb + tokg * HD + dd);
        *(float4*)(sl + 4) = *(const float4*)(sinb + tokg * HD + dd + 4);
        *(float4*)ch = *(const float4*)(cosb + tokg * HD + dd + 40);
        *(float4*)(ch + 4) = *(const float4*)(cosb + tokg * HD + dd + 44);
        *(float4*)sh = *(const float4*)(sinb + tokg * HD + dd + 40);
        *(float4*)(sh + 4) = *(const float4*)(sinb + tokg * HD + dd + 44);
        ushort8 olo, ohi;
#pragma unroll
        for (int j = 0; j < 8; ++j) {
            const float x1 = bf2f((unsigned short)lo[j]);
            const float x2 = bf2f((unsigned short)hi[j]);
            float rl = x1 * cl[j] - x2 * sl[j];
            float rh = x2 * ch[j] + x1 * sh[j];
            if (qk == 0) { rl *= scale; rh *= scale; }
            olo[j] = f2bf(rl);
            ohi[j] = f2bf(rh);
        }
        unsigned short* base = (qk ? Ks : Qs) + tok * 104 + dd;
        *(ushort8*)base = olo;
        *(ushort8*)(base + 40) = ohi;
    }
    {
        const int tile = t >> 7, row = (t >> 1) & 63, half = t & 1;
        ushort8 z = (ushort8)0;
        *(ushort8*)((tile ? Ks : Qs) + row * 104 + 80 + half * 8) = z;
    }
    for (int c = t; c < 640; c += 256) {
        const int tok = c / 10;
        const int dd = (c % 10) * 8;
        const bf16x8 vv = *(const bf16x8*)(qkv +
            (size_t)(win * 64 + tok) * QKV_N + h * HD + 2 * DIM + dd);
#pragma unroll
        for (int j = 0; j < 8; ++j)
            Vt[(dd + j) * 88 + tok] = (unsigned short)vv[j];
    }
    __syncthreads();

    f32x4 acc[4];
#pragma unroll
    for (int n = 0; n < 4; ++n) acc[n] = (f32x4){0.f, 0.f, 0.f, 0.f};
#pragma unroll
    for (int ks = 0; ks < 3; ++ks) {
        const int k0 = ks * 32;
        const bf16x8 af = *(const bf16x8*)(Qs + (w * 16 + l15) * 104 + k0 + g * 8);
#pragma unroll
        for (int n = 0; n < 4; ++n) {
            const bf16x8 bfr = *(const bf16x8*)(Ks + (n * 16 + l15) * 104 + k0 + g * 8);
            acc[n] = __builtin_amdgcn_mfma_f32_16x16x32_bf16(af, bfr, acc[n], 0, 0, 0);
        }
    }

    const float* mp = mask + (size_t)win * 4096;
    float pr[4][4];
#pragma unroll
    for (int r = 0; r < 4; ++r) {
        const int row = w * 16 + g * 4 + r;
        float v[4];
#pragma unroll
        for (int n = 0; n < 4; ++n)
            v[n] = acc[n][r] + mp[row * 64 + n * 16 + l15];
        float mx = fmaxf(fmaxf(v[0], v[1]), fmaxf(v[2], v[3]));
        mx = fmaxf(mx, __shfl_xor(mx, 1));
        mx = fmaxf(mx, __shfl_xor(mx, 2));
        mx = fmaxf(mx, __shfl_xor(mx, 4));
        mx = fmaxf(mx, __shfl_xor(mx, 8));
        float sum = 0.f;
#pragma unroll
        for (int n = 0; n < 4; ++n) { v[n] = __expf(v[n] - mx); sum += v[n]; }
        sum += __shfl_xor(sum, 1);
        sum += __shfl_xor(sum, 2);
        sum += __shfl_xor(sum, 4);
        sum += __shfl_xor(sum, 8);
        const float inv = 1.0f / sum;
#pragma unroll
        for (int n = 0; n < 4; ++n) pr[r][n] = v[n] * inv;
    }

    __syncthreads();
#pragma unroll
    for (int r = 0; r < 4; ++r)
#pragma unroll
        for (int n = 0; n < 4; ++n)
            P[(w * 16 + g * 4 + r) * 72 + n * 16 + l15] = f2bf(pr[r][n]);
    __syncthreads();

    f32x4 ao[5];
#pragma unroll
    for (int n = 0; n < 5; ++n) ao[n] = (f32x4){0.f, 0.f, 0.f, 0.f};
#pragma unroll
    for (int ks = 0; ks < 2; ++ks) {
        const int k0 = ks * 32;
        const bf16x8 pa = *(const bf16x8*)(P + (w * 16 + l15) * 72 + k0 + g * 8);
#pragma unroll
        for (int n = 0; n < 5; ++n) {
            const bf16x8 bv = *(const bf16x8*)(Vt + (n * 16 + l15) * 88 + k0 + g * 8);
            ao[n] = __builtin_amdgcn_mfma_f32_16x16x32_bf16(pa, bv, ao[n], 0, 0, 0);
        }
    }

#pragma unroll
    for (int n = 0; n < 5; ++n)
#pragma unroll
        for (int r = 0; r < 4; ++r) {
            const int row = win * 64 + w * 16 + g * 4 + r;
            attn_out[(size_t)row * DIM + h * HD + n * 16 + l15] = f2bf(ao[n][r]);
        }
}

// ---------------------------------------------------------------------------
extern "C" void kernel_launch(void* const* d_in, const int* in_sizes, int n_in,
                              void* d_out, int out_size, void* d_ws, size_t ws_size,
                              hipStream_t stream) {
    const float* hidden = (const float*)d_in[0];
    const float* masks  = (const float*)d_in[1];
    const float* cosb   = (const float*)d_in[2];
    const float* sinb   = (const float*)d_in[3];
    const float* qkv_w  = (const float*)d_in[4];
    const float* qkv_b  = (const float*)d_in[5];
    const float* proj_w = (const float*)d_in[6];
    const float* proj_b = (const float*)d_in[7];
    float* out = (float*)d_out;

    unsigned short* qkv_bf    = (unsigned short*)d_ws;                  // [SEQ][3840]
    unsigned short* attn_bf   = qkv_bf    + (size_t)SEQ * QKV_N;        // [SEQ][1280]
    unsigned short* hidden_bf = attn_bf   + (size_t)SEQ * DIM;          // [SEQ][1280]
    unsigned short* qkvw_bf   = hidden_bf + (size_t)SEQ * DIM;          // [3840][1280]
    unsigned short* projw_bf  = qkvw_bf   + (size_t)QKV_N * DIM;        // [1280][1280]

    {
        const long n0 = (long)SEQ * DIM;
        const long n1 = (long)QKV_N * DIM;
        const long n2 = (long)DIM * DIM;
        cvt_f32_bf16<<<(int)(n0 / (8 * 256)), 256, 0, stream>>>(hidden, hidden_bf, n0);
        cvt_f32_bf16<<<(int)(n1 / (8 * 256)), 256, 0, stream>>>(qkv_w, qkvw_bf, n1);
        cvt_f32_bf16<<<(int)(n2 / (8 * 256)), 256, 0, stream>>>(proj_w, projw_bf, n2);
    }
    {   // QKV projection: 64 x 15 = 960 blocks, 256x256 tiles (r9 kernel)
        gemm_nt_bf16_sp<1><<<dim3(960), 512, 0, stream>>>(
            hidden_bf, qkvw_bf, qkv_b, (void*)qkv_bf, QKV_N, QKV_N / 256);
    }
    {
        dim3 grid(NHEAD, NWIN);
        win_attn_mfma<<<grid, 256, 0, stream>>>(qkv_bf, cosb, sinb, masks, attn_bf);
    }
    {   // output projection: 128 x 10 = 1280 blocks, 128x128 tiles, 2/CU
        gemm_nt_bf16_t2<0><<<dim3(1280), 256, 0, stream>>>(
            attn_bf, projw_bf, proj_b, (void*)out, DIM, DIM / 128);
    }
}

// Round 12
// 312.643 us; speedup vs baseline: 1.0915x; 1.0204x over previous
//
#include <hip/hip_runtime.h>
#include <hip/hip_bf16.h>

#define SEQ 16384
#define DIM 1280
#define NHEAD 16
#define HD 80
#define NWIN 256   // SEQ / 64
#define QKV_N 3840 // 3 * DIM
#define GK 1280    // K of both GEMMs
#define NT 20      // GK / 64

typedef __attribute__((ext_vector_type(8))) short bf16x8;
typedef __attribute__((ext_vector_type(8))) unsigned short ushort8;
typedef __attribute__((ext_vector_type(4))) float f32x4;

__device__ inline unsigned short f2bf(float x) {
    union { __hip_bfloat16 b; unsigned short u; } cv;
    cv.b = __float2bfloat16(x);
    return cv.u;
}
__device__ inline float bf2f(unsigned short u) {
    union { unsigned int i; float f; } cv;
    cv.i = ((unsigned int)u) << 16;
    return cv.f;
}

// async global->LDS, 16B per lane, wave-uniform LDS base + lane*16
#define GLD16(g, l) __builtin_amdgcn_global_load_lds( \
    (const __attribute__((address_space(1))) void*)(g), \
    (__attribute__((address_space(3))) void*)(l), 16, 0, 0)

#define SBAR() asm volatile("s_barrier" ::: "memory")

// ---------------------------------------------------------------------------
// merged f32 -> bf16 convert for all three buffers (one dispatch).
// Segment boundaries in 2048-elem block units (compile-time sizes).
// ---------------------------------------------------------------------------
#define CVT_B0 10240   // SEQ*DIM      / 2048
#define CVT_B1 12640   // + QKV_N*DIM  / 2048
#define CVT_B2 13440   // + DIM*DIM    / 2048
__global__ __launch_bounds__(256) void cvt_all(
    const float* __restrict__ s0, unsigned short* __restrict__ d0,
    const float* __restrict__ s1, unsigned short* __restrict__ d1,
    const float* __restrict__ s2, unsigned short* __restrict__ d2)
{
    const int b = blockIdx.x;
    const float* s; unsigned short* d; long off;
    if (b < CVT_B0)      { s = s0; d = d0; off = (long)b * 2048; }
    else if (b < CVT_B1) { s = s1; d = d1; off = (long)(b - CVT_B0) * 2048; }
    else                 { s = s2; d = d2; off = (long)(b - CVT_B1) * 2048; }
    const long i = off + (long)threadIdx.x * 8;
    const float4 a = *(const float4*)(s + i);
    const float4 c = *(const float4*)(s + i + 4);
    ushort8 o;
    o[0] = f2bf(a.x); o[1] = f2bf(a.y); o[2] = f2bf(a.z); o[3] = f2bf(a.w);
    o[4] = f2bf(c.x); o[5] = f2bf(c.y); o[6] = f2bf(c.z); o[7] = f2bf(c.w);
    *(ushort8*)(d + i) = o;
}

// ---------------------------------------------------------------------------
// Tail-exact BN-parametric bf16 MFMA NT-GEMM (generalization of r11's t2,
// which passed with BN=128): out[M][N] = A[M][K] @ B[N][K]^T + bias.
// 128xBN tile, BK=64, 256 threads = 4 waves (2Mx2N), per-wave 64 x BN/2
// (4 m-frags x NF=BN/32 n-frags, acc = 16*NF VGPR). LDS = (128+BN)*64*2B
// double-buffered: BN=192 -> 80 KiB (2 blocks/CU = exactly 160 KiB);
// BN=160 -> 72 KiB (2 blocks/CU). Grid shapes chosen for EXACT capacity
// rounds: QKV 128x20=2560 @2/CU = 5.00 rounds; proj 128x8=1024 = 2.00.
// Single-barrier counted loop (r7-proven race-freedom); 3-bit both-sides
// XOR swizzle on 64-elem rows (the measured-conflict-free configuration);
// T1 XCD swizzle (grids %8==0); T5 setprio.
// ---------------------------------------------------------------------------
template <int BN, int OUT_BF16>
__global__ __launch_bounds__(256, 2) void gemm_nt_bf16_g(
    const unsigned short* __restrict__ A,   // [M][GK] bf16
    const unsigned short* __restrict__ B,   // [N][GK] bf16
    const float* __restrict__ bias,         // [N]
    void* __restrict__ outp,                // [M][N] f32 or bf16
    int N, int nbx)                         // nbx = N/BN
{
    constexpr int NF   = BN / 32;           // n-frags per wave
    constexpr int BBLK = BN / 32;           // B 32-row stage blocks
    constexpr int REG  = (128 + BN) * 64;   // region elems

    __shared__ unsigned short sh[2 * REG];

    const int t = threadIdx.x;
    const int w = t >> 6;
    const int lane = t & 63;
    const int l15 = lane & 15;
    const int g = lane >> 4;

    // T1: XCD swizzle (gridDim.x multiple of 8)
    const int cpx = gridDim.x >> 3;
    const int bid = blockIdx.x;
    const int wg = (bid & 7) * cpx + (bid >> 3);
    const int bm = (wg / nbx) * 128;
    const int bn = (wg % nbx) * BN;

    const int wr = (w >> 1) * 64;           // wave rows [wr, wr+64)
    const int wc = (w & 1) * (BN / 2);      // wave cols [wc, wc+BN/2)

    // staging: 32-row blocks; thread t covers row t>>3, 16B slot t&7.
    // Pre-swizzled source col = slot*8 ^ ((row&7)<<3)  (elements).
    const int tr = t >> 3;
    const int colsw = ((t & 7) * 8) ^ (((t >> 3) & 7) << 3);
    const unsigned short* gA[4];
    const unsigned short* gB[BBLK];
#pragma unroll
    for (int j = 0; j < 4; ++j)
        gA[j] = A + (size_t)(bm + j * 32 + tr) * GK + colsw;
#pragma unroll
    for (int j = 0; j < BBLK; ++j)
        gB[j] = B + (size_t)(bn + j * 32 + tr) * GK + colsw;
    const int wub = (t & ~63) * 8;          // wave-uniform LDS elem base

    // ds_read frag offsets: LDS[row*64 + e] = global[row][e ^ ((row&7)<<3)]
    // k-chunk kk reads e = (kk*32 + g*8) ^ sw  (XOR of the FULL offset)
    const int sw = (l15 & 7) << 3;
    const int fk0 = (g * 8) ^ sw;
    const int fk1 = (32 + g * 8) ^ sw;
    int arow[4], brow[NF];
#pragma unroll
    for (int mi = 0; mi < 4; ++mi) arow[mi] = (wr + mi * 16 + l15) * 64;
#pragma unroll
    for (int ni = 0; ni < NF; ++ni) brow[ni] = 8192 + (wc + ni * 16 + l15) * 64;

    f32x4 acc[4][NF];
#pragma unroll
    for (int mi = 0; mi < 4; ++mi)
#pragma unroll
        for (int ni = 0; ni < NF; ++ni)
            acc[mi][ni] = (f32x4){0.f, 0.f, 0.f, 0.f};

    // stage all chunks of K-tile `tile` into region tile&1
    auto stageTile = [&](int tile) {
        if (tile >= NT) return;
        unsigned short* rg = sh + (tile & 1) * REG + wub;
        const int ka = tile * 64;
#pragma unroll
        for (int j = 0; j < 4; ++j)
            GLD16(gA[j] + ka, rg + j * 2048);
#pragma unroll
        for (int j = 0; j < BBLK; ++j)
            GLD16(gB[j] + ka, rg + 8192 + j * 2048);
    };

    bf16x8 af0[4], af1[4], bf0[NF], bf1[NF];

#define MFMA_PASS(AF, BF)                                                     \
    __builtin_amdgcn_s_setprio(1);                                            \
    _Pragma("unroll") for (int mi = 0; mi < 4; ++mi)                          \
    _Pragma("unroll") for (int ni = 0; ni < NF; ++ni)                         \
        acc[mi][ni] = __builtin_amdgcn_mfma_f32_16x16x32_bf16(                \
            (AF)[mi], (BF)[ni], acc[mi][ni], 0, 0, 0);                        \
    __builtin_amdgcn_s_setprio(0);

    stageTile(0);

    for (int kt = 0; kt < NT; ++kt) {
        const unsigned short* base = sh + (kt & 1) * REG;

        asm volatile("s_waitcnt vmcnt(0)" ::: "memory");  // tile kt staged
        SBAR();                                           // block-wide visible
        stageTile(kt + 1);                                // region ~cur only

        // read kk0 + kk1 frags up-front, then two MFMA passes (t2 pattern:
        // compiler overlaps kk1 reads under kk0 MFMAs via partial lgkmcnt)
#pragma unroll
        for (int ni = 0; ni < NF; ++ni) bf0[ni] = *(const bf16x8*)(base + brow[ni] + fk0);
#pragma unroll
        for (int mi = 0; mi < 4; ++mi) af0[mi] = *(const bf16x8*)(base + arow[mi] + fk0);
#pragma unroll
        for (int ni = 0; ni < NF; ++ni) bf1[ni] = *(const bf16x8*)(base + brow[ni] + fk1);
#pragma unroll
        for (int mi = 0; mi < 4; ++mi) af1[mi] = *(const bf16x8*)(base + arow[mi] + fk1);
        MFMA_PASS(af0, bf0);
        MFMA_PASS(af1, bf1);
    }
#undef MFMA_PASS

    // ---- epilogue: C/D layout col=l15, row=g*4+reg ----
    const int orow = bm + wr + g * 4;
    const int ocol = bn + wc + l15;
    float bv[NF];
#pragma unroll
    for (int ni = 0; ni < NF; ++ni) bv[ni] = bias[ocol + ni * 16];
#pragma unroll
    for (int mi = 0; mi < 4; ++mi)
#pragma unroll
        for (int ni = 0; ni < NF; ++ni)
#pragma unroll
            for (int r = 0; r < 4; ++r) {
                const int row = orow + mi * 16 + r;
                const int col = ocol + ni * 16;
                const float v = acc[mi][ni][r] + bv[ni];
                if (OUT_BF16)
                    ((unsigned short*)outp)[(size_t)row * N + col] = f2bf(v);
                else
                    ((float*)outp)[(size_t)row * N + col] = v;
            }
}

// ---------------------------------------------------------------------------
// MFMA windowed attention (unchanged; ~55 us)
// ---------------------------------------------------------------------------
__global__ __launch_bounds__(256) void win_attn_mfma(
    const unsigned short* __restrict__ qkv,  // [S][3840] bf16
    const float* __restrict__ cosb,          // [S][80]
    const float* __restrict__ sinb,          // [S][80]
    const float* __restrict__ mask,          // [NWIN][64][64]
    unsigned short* __restrict__ attn_out)   // [S][1280] bf16
{
    const int h = blockIdx.x;
    const int win = blockIdx.y;
    const int t = threadIdx.x;
    const int w = t >> 6;
    const int lane = t & 63;
    const int l15 = lane & 15;
    const int g = lane >> 4;

    __shared__ unsigned short Qs[64 * 104];
    __shared__ unsigned short Ks[64 * 104];
    __shared__ unsigned short Vt[80 * 88];
    unsigned short* P = Qs;

    const float scale = 0.11180339887498949f;  // 1/sqrt(80)

    for (int c = t; c < 640; c += 256) {
        const int qk = c / 320;
        const int cc = c % 320;
        const int tok = cc / 5;
        const int dd = (cc % 5) * 8;
        const int tokg = win * 64 + tok;
        const size_t gb = (size_t)tokg * QKV_N + h * HD + qk * DIM;
        const bf16x8 lo = *(const bf16x8*)(qkv + gb + dd);
        const bf16x8 hi = *(const bf16x8*)(qkv + gb + dd + 40);
        float cl[8], sl[8], ch[8], sh[8];
        *(float4*)cl = *(const float4*)(cosb + tokg * HD + dd);
        *(float4*)(cl + 4) = *(const float4*)(cosb + tokg * HD + dd + 4);
        *(float4*)sl = *(const float4*)(sinb + tokg * HD + dd);
        *(float4*)(sl + 4) = *(const float4*)(sinb + tokg * HD + dd + 4);
        *(float4*)ch = *(const float4*)(cosb + tokg * HD + dd + 40);
        *(float4*)(ch + 4) = *(const float4*)(cosb + tokg * HD + dd + 44);
        *(float4*)sh = *(const float4*)(sinb + tokg * HD + dd + 40);
        *(float4*)(sh + 4) = *(const float4*)(sinb + tokg * HD + dd + 44);
        ushort8 olo, ohi;
#pragma unroll
        for (int j = 0; j < 8; ++j) {
            const float x1 = bf2f((unsigned short)lo[j]);
            const float x2 = bf2f((unsigned short)hi[j]);
            float rl = x1 * cl[j] - x2 * sl[j];
            float rh = x2 * ch[j] + x1 * sh[j];
            if (qk == 0) { rl *= scale; rh *= scale; }
            olo[j] = f2bf(rl);
            ohi[j] = f2bf(rh);
        }
        unsigned short* base = (qk ? Ks : Qs) + tok * 104 + dd;
        *(ushort8*)base = olo;
        *(ushort8*)(base + 40) = ohi;
    }
    {
        const int tile = t >> 7, row = (t >> 1) & 63, half = t & 1;
        ushort8 z = (ushort8)0;
        *(ushort8*)((tile ? Ks : Qs) + row * 104 + 80 + half * 8) = z;
    }
    for (int c = t; c < 640; c += 256) {
        const int tok = c / 10;
        const int dd = (c % 10) * 8;
        const bf16x8 vv = *(const bf16x8*)(qkv +
            (size_t)(win * 64 + tok) * QKV_N + h * HD + 2 * DIM + dd);
#pragma unroll
        for (int j = 0; j < 8; ++j)
            Vt[(dd + j) * 88 + tok] = (unsigned short)vv[j];
    }
    __syncthreads();

    f32x4 acc[4];
#pragma unroll
    for (int n = 0; n < 4; ++n) acc[n] = (f32x4){0.f, 0.f, 0.f, 0.f};
#pragma unroll
    for (int ks = 0; ks < 3; ++ks) {
        const int k0 = ks * 32;
        const bf16x8 af = *(const bf16x8*)(Qs + (w * 16 + l15) * 104 + k0 + g * 8);
#pragma unroll
        for (int n = 0; n < 4; ++n) {
            const bf16x8 bfr = *(const bf16x8*)(Ks + (n * 16 + l15) * 104 + k0 + g * 8);
            acc[n] = __builtin_amdgcn_mfma_f32_16x16x32_bf16(af, bfr, acc[n], 0, 0, 0);
        }
    }

    const float* mp = mask + (size_t)win * 4096;
    float pr[4][4];
#pragma unroll
    for (int r = 0; r < 4; ++r) {
        const int row = w * 16 + g * 4 + r;
        float v[4];
#pragma unroll
        for (int n = 0; n < 4; ++n)
            v[n] = acc[n][r] + mp[row * 64 + n * 16 + l15];
        float mx = fmaxf(fmaxf(v[0], v[1]), fmaxf(v[2], v[3]));
        mx = fmaxf(mx, __shfl_xor(mx, 1));
        mx = fmaxf(mx, __shfl_xor(mx, 2));
        mx = fmaxf(mx, __shfl_xor(mx, 4));
        mx = fmaxf(mx, __shfl_xor(mx, 8));
        float sum = 0.f;
#pragma unroll
        for (int n = 0; n < 4; ++n) { v[n] = __expf(v[n] - mx); sum += v[n]; }
        sum += __shfl_xor(sum, 1);
        sum += __shfl_xor(sum, 2);
        sum += __shfl_xor(sum, 4);
        sum += __shfl_xor(sum, 8);
        const float inv = 1.0f / sum;
#pragma unroll
        for (int n = 0; n < 4; ++n) pr[r][n] = v[n] * inv;
    }

    __syncthreads();
#pragma unroll
    for (int r = 0; r < 4; ++r)
#pragma unroll
        for (int n = 0; n < 4; ++n)
            P[(w * 16 + g * 4 + r) * 72 + n * 16 + l15] = f2bf(pr[r][n]);
    __syncthreads();

    f32x4 ao[5];
#pragma unroll
    for (int n = 0; n < 5; ++n) ao[n] = (f32x4){0.f, 0.f, 0.f, 0.f};
#pragma unroll
    for (int ks = 0; ks < 2; ++ks) {
        const int k0 = ks * 32;
        const bf16x8 pa = *(const bf16x8*)(P + (w * 16 + l15) * 72 + k0 + g * 8);
#pragma unroll
        for (int n = 0; n < 5; ++n) {
            const bf16x8 bv = *(const bf16x8*)(Vt + (n * 16 + l15) * 88 + k0 + g * 8);
            ao[n] = __builtin_amdgcn_mfma_f32_16x16x32_bf16(pa, bv, ao[n], 0, 0, 0);
        }
    }

#pragma unroll
    for (int n = 0; n < 5; ++n)
#pragma unroll
        for (int r = 0; r < 4; ++r) {
            const int row = win * 64 + w * 16 + g * 4 + r;
            attn_out[(size_t)row * DIM + h * HD + n * 16 + l15] = f2bf(ao[n][r]);
        }
}

// ---------------------------------------------------------------------------
extern "C" void kernel_launch(void* const* d_in, const int* in_sizes, int n_in,
                              void* d_out, int out_size, void* d_ws, size_t ws_size,
                              hipStream_t stream) {
    const float* hidden = (const float*)d_in[0];
    const float* masks  = (const float*)d_in[1];
    const float* cosb   = (const float*)d_in[2];
    const float* sinb   = (const float*)d_in[3];
    const float* qkv_w  = (const float*)d_in[4];
    const float* qkv_b  = (const float*)d_in[5];
    const float* proj_w = (const float*)d_in[6];
    const float* proj_b = (const float*)d_in[7];
    float* out = (float*)d_out;

    unsigned short* qkv_bf    = (unsigned short*)d_ws;                  // [SEQ][3840]
    unsigned short* attn_bf   = qkv_bf    + (size_t)SEQ * QKV_N;        // [SEQ][1280]
    unsigned short* hidden_bf = attn_bf   + (size_t)SEQ * DIM;          // [SEQ][1280]
    unsigned short* qkvw_bf   = hidden_bf + (size_t)SEQ * DIM;          // [3840][1280]
    unsigned short* projw_bf  = qkvw_bf   + (size_t)QKV_N * DIM;        // [1280][1280]

    // 0) merged f32->bf16 converts (one dispatch)
    cvt_all<<<dim3(CVT_B2), 256, 0, stream>>>(hidden, hidden_bf,
                                              qkv_w, qkvw_bf,
                                              proj_w, projw_bf);

    // 1) QKV projection: 128x192 tiles -> 128 x 20 = 2560 blocks @2/CU
    //    = 5.00 capacity rounds exact
    gemm_nt_bf16_g<192, 1><<<dim3(2560), 256, 0, stream>>>(
        hidden_bf, qkvw_bf, qkv_b, (void*)qkv_bf, QKV_N, QKV_N / 192);

    // 2) windowed attention (RoPE fused)
    {
        dim3 grid(NHEAD, NWIN);
        win_attn_mfma<<<grid, 256, 0, stream>>>(qkv_bf, cosb, sinb, masks, attn_bf);
    }

    // 3) output projection: 128x160 tiles -> 128 x 8 = 1024 blocks @2/CU
    //    = 2.00 capacity rounds exact
    gemm_nt_bf16_g<160, 0><<<dim3(1024), 256, 0, stream>>>(
        attn_bf, projw_bf, proj_b, (void*)out, DIM, DIM / 160);
}